// Round 3
// baseline (660.579 us; speedup 1.0000x reference)
//
#include <hip/hip_runtime.h>

// ---------------------------------------------------------------------------
// SpatialTransformerPyramid2d fused kernel, round 3.
// N=64, c=32, H=W=128, outdims=4096, SCALE_N=4 (levels hi0..hi3, lo4).
//
// Identities:
//   sample(hi_{j-1}) = bilin(img_{j-1}) - 4*stencil_{j-1}(lo_j)
//   bilinear taps of level j lie inside the 3-tap transposed-conv support
//   from level j-1, so per level j we read ONE 3x3 patch of lo_j and form two
//   weighted sums (a = stencil for hi_{j-1}, b = bilinear for hi_j/lo4).
//   => per (out,ch): 4 global taps (x) + 4 levels * 9 LDS taps.
//
// Round-3 structure: block = (n, channel), 256 threads, 2048 blocks.
// LDS = 22240 B/block.  __launch_bounds__(256,6): 6 blocks/CU = 24 waves/CU
// (75% occupancy cap), VGPR cap ~85 -- round-1 code fit in 84, NO SPILLS
// (round 2's (512,6) forced 40 VGPRs and spilled 1.6 GB to scratch).
// ---------------------------------------------------------------------------

#define P1 65
#define P2 33
#define P3 17
#define P4 9
#define OFF_LO1 0                      // 64 rows * 65 = 4160
#define OFF_LO2 4160                   // 32 * 33 = 1056
#define OFF_LO3 5216                   // 16 * 17 = 272
#define OFF_LO4 5488                   // 8 * 9   = 72
#define SLOT    5560                   // floats per channel slot (22240 B)

#define G_A 0.0613609f
#define G_B 0.2447700f
#define G_C 0.3877386f

static __device__ __forceinline__ float clampf(float v, float lo, float hi) {
    return fminf(fmaxf(v, lo), hi);
}
static __device__ __forceinline__ int imin(int a, int b) { return a < b ? a : b; }
static __device__ __forceinline__ int imax(int a, int b) { return a > b ? a : b; }

__global__ void init_out_kernel(const float* __restrict__ bias, float* __restrict__ y) {
    int i = blockIdx.x * blockDim.x + threadIdx.x;
    y[i] = bias[i & 4095];
}

// smooth+downsample one point from an LDS source with row stride `stride`,
// logical size S x S, zero padding outside.
static __device__ __forceinline__ float down_pt_lds(const float* s, int stride, int S,
                                                    int i, int j) {
    const float g1[5] = {G_A, G_B, G_C, G_B, G_A};
    int by = 2 * i - 2, bx = 2 * j - 2;
    float acc = 0.f;
    if (by >= 0 && by + 4 < S && bx >= 0 && bx + 4 < S) {
#pragma unroll
        for (int dy = 0; dy < 5; ++dy) {
            const float* r = s + (by + dy) * stride + bx;
            acc += g1[dy] * (G_A * (r[0] + r[4]) + G_B * (r[1] + r[3]) + G_C * r[2]);
        }
    } else {
#pragma unroll
        for (int dy = 0; dy < 5; ++dy) {
            int yy = by + dy;
            if ((unsigned)yy < (unsigned)S) {
#pragma unroll
                for (int dx = 0; dx < 5; ++dx) {
                    int xx = bx + dx;
                    if ((unsigned)xx < (unsigned)S)
                        acc += g1[dy] * g1[dx] * s[yy * stride + xx];
                }
            }
        }
    }
    return acc;
}

__global__ __launch_bounds__(256, 6) void pyr_sample_kernel(
    const float* __restrict__ x, const float* __restrict__ grid,
    const float* __restrict__ feat, float* __restrict__ y)
{
    __shared__ float s_lo[SLOT];
    const int tid = threadIdx.x;
    const int n   = blockIdx.x >> 5;   // 64
    const int c   = blockIdx.x & 31;   // 32
    const float* img = x + ((size_t)(n * 32 + c) << 14); // 128*128

    const float g1[5] = {G_A, G_B, G_C, G_B, G_A};

    // ---- phase 1: lo1 (64x64), runs of 4 adjacent points -------------------
    for (int p = tid; p < 1024; p += 256) {
        int i = p >> 4, j0 = (p & 15) << 2;
        int by = 2 * i - 2, bx = 2 * j0 - 2;
        float acc[4] = {0.f, 0.f, 0.f, 0.f};
        if (i >= 1 && i <= 62 && j0 >= 4 && j0 <= 56) {
#pragma unroll
            for (int dy = 0; dy < 5; ++dy) {
                const float* row = img + (by + dy) * 128 + bx;
                float v[11];
#pragma unroll
                for (int t = 0; t < 11; ++t) v[t] = row[t];
                float g = g1[dy];
#pragma unroll
                for (int jj = 0; jj < 4; ++jj) {
                    float h = G_A * (v[2 * jj] + v[2 * jj + 4]) +
                              G_B * (v[2 * jj + 1] + v[2 * jj + 3]) +
                              G_C * v[2 * jj + 2];
                    acc[jj] += g * h;
                }
            }
        } else {
#pragma unroll
            for (int dy = 0; dy < 5; ++dy) {
                int yy = by + dy;
                if ((unsigned)yy < 128u) {
#pragma unroll
                    for (int t = 0; t < 11; ++t) {
                        int xx = bx + t;
                        if ((unsigned)xx < 128u) {
                            float v = img[yy * 128 + xx];
#pragma unroll
                            for (int jj = 0; jj < 4; ++jj) {
                                int dx = t - 2 * jj;
                                if (dx >= 0 && dx <= 4) acc[jj] += g1[dy] * g1[dx] * v;
                            }
                        }
                    }
                }
            }
        }
        int base = OFF_LO1 + i * P1 + j0;
#pragma unroll
        for (int jj = 0; jj < 4; ++jj) s_lo[base + jj] = acc[jj];
    }
    __syncthreads();

    // ---- phase 2: lo2 (32x32) ----
    for (int p = tid; p < 1024; p += 256) {
        int i = p >> 5, j = p & 31;
        s_lo[OFF_LO2 + i * P2 + j] = down_pt_lds(s_lo + OFF_LO1, P1, 64, i, j);
    }
    __syncthreads();

    // ---- phase 3: lo3 (16x16) ----
    {
        int i = tid >> 4, j = tid & 15;
        s_lo[OFF_LO3 + i * P3 + j] = down_pt_lds(s_lo + OFF_LO2, P2, 32, i, j);
    }
    __syncthreads();

    // ---- phase 4: lo4 (8x8) ----
    if (tid < 64) {
        int i = tid >> 3, j = tid & 7;
        s_lo[OFF_LO4 + i * P4 + j] = down_pt_lds(s_lo + OFF_LO3, P3, 16, i, j);
    }
    __syncthreads();

    // ---- phase 5: sample + contract ----
    const float2* g2 = (const float2*)grid;
    float* yrow = y + ((size_t)n << 12);
    for (int out = tid; out < 4096; out += 256) {
        float2 gv = g2[out];
        float xs = clampf(gv.x, -1.f, 1.f);
        float ys = clampf(gv.y, -1.f, 1.f);

        float fk[5];
#pragma unroll
        for (int k = 0; k < 5; ++k)
            fk[k] = feat[((size_t)(k * 32 + c) << 12) + out];

        // ---- level 0: bilinear on x (global) ----
        float fx = (xs + 1.f) * 64.f - 0.5f;
        float fy = (ys + 1.f) * 64.f - 0.5f;
        float x0f = floorf(fx), y0f = floorf(fy);
        int x0 = (int)x0f, y0 = (int)y0f;
        float wx = fx - x0f, wy = fy - y0f;
        float ux0 = (x0 >= 0)      ? (1.f - wx) : 0.f;
        float ux1 = (x0 + 1 < 128) ? wx         : 0.f;
        float uy0 = (y0 >= 0)      ? (1.f - wy) : 0.f;
        float uy1 = (y0 + 1 < 128) ? wy         : 0.f;
        int cx0 = imax(x0, 0), cx1 = imin(x0 + 1, 127);
        int cy0 = imax(y0, 0), cy1 = imin(y0 + 1, 127);

        float acc;
        {
            float v = ux0 * uy0 * img[cy0 * 128 + cx0] + ux1 * uy0 * img[cy0 * 128 + cx1] +
                      ux0 * uy1 * img[cy1 * 128 + cx0] + ux1 * uy1 * img[cy1 * 128 + cx1];
            acc = fk[0] * v;
        }

        // rolling "previous level" bilinear state
        int   x0p = x0, y0p = y0;
        float ux0p = ux0, ux1p = ux1, uy0p = uy0, uy1p = uy1;

#pragma unroll
        for (int j = 1; j <= 4; ++j) {
            const int Wj  = 128 >> j;
            const int Pj  = (j == 1) ? P1 : (j == 2) ? P2 : (j == 3) ? P3 : P4;
            const int off = (j == 1) ? OFF_LO1 : (j == 2) ? OFF_LO2
                          : (j == 3) ? OFF_LO3 : OFF_LO4;

            // a-weights: -4*up stencil from level j-1 corner pair
            int qx; float ax0, ax1, ax2;
            if (x0p & 1) { qx = (x0p - 1) >> 1;
                ax0 = G_B * ux0p + G_A * ux1p; ax1 = G_B * ux0p + G_C * ux1p; ax2 = G_A * ux1p; }
            else         { qx = (x0p >> 1) - 1;
                ax0 = G_A * ux0p; ax1 = G_C * ux0p + G_B * ux1p; ax2 = G_A * ux0p + G_B * ux1p; }
            int qy; float ay0, ay1, ay2;
            if (y0p & 1) { qy = (y0p - 1) >> 1;
                ay0 = G_B * uy0p + G_A * uy1p; ay1 = G_B * uy0p + G_C * uy1p; ay2 = G_A * uy1p; }
            else         { qy = (y0p >> 1) - 1;
                ay0 = G_A * uy0p; ay1 = G_C * uy0p + G_B * uy1p; ay2 = G_A * uy0p + G_B * uy1p; }

            // level-j bilinear params
            float fxj = (xs + 1.f) * (float)(Wj >> 1) - 0.5f;
            float fyj = (ys + 1.f) * (float)(Wj >> 1) - 0.5f;
            float x0jf = floorf(fxj), y0jf = floorf(fyj);
            int x0j = (int)x0jf, y0j = (int)y0jf;
            float wxj = fxj - x0jf, wyj = fyj - y0jf;
            float ux0j = (x0j >= 0)     ? (1.f - wxj) : 0.f;
            float ux1j = (x0j + 1 < Wj) ? wxj         : 0.f;
            float uy0j = (y0j >= 0)     ? (1.f - wyj) : 0.f;
            float uy1j = (y0j + 1 < Wj) ? wyj         : 0.f;

            // b-weights: level-j bilinear folded into the 3-tap frame
            float bx0 = 0.f, bx1 = 0.f, bx2 = 0.f;
            int posx = imin(imax(x0j - qx, 0), 1);
            if (posx == 0) { bx0 = ux0j; bx1 = ux1j; } else { bx1 = ux0j; bx2 = ux1j; }
            float by0 = 0.f, by1 = 0.f, by2 = 0.f;
            int posy = imin(imax(y0j - qy, 0), 1);
            if (posy == 0) { by0 = uy0j; by1 = uy1j; } else { by1 = uy0j; by2 = uy1j; }

            // tap indices, OOB -> zero weight + clamped index
            int tx0, tx1, tx2, ty0, ty1, ty2;
            {
                int ix0 = qx, ix1 = qx + 1, ix2 = qx + 2;
                if (ix0 < 0 || ix0 >= Wj) { ax0 = 0.f; bx0 = 0.f; }
                if (ix1 < 0 || ix1 >= Wj) { ax1 = 0.f; bx1 = 0.f; }
                if (ix2 < 0 || ix2 >= Wj) { ax2 = 0.f; bx2 = 0.f; }
                tx0 = imin(imax(ix0, 0), Wj - 1);
                tx1 = imin(imax(ix1, 0), Wj - 1);
                tx2 = imin(imax(ix2, 0), Wj - 1);
                int iy0 = qy, iy1 = qy + 1, iy2 = qy + 2;
                if (iy0 < 0 || iy0 >= Wj) { ay0 = 0.f; by0 = 0.f; }
                if (iy1 < 0 || iy1 >= Wj) { ay1 = 0.f; by1 = 0.f; }
                if (iy2 < 0 || iy2 >= Wj) { ay2 = 0.f; by2 = 0.f; }
                ty0 = imin(imax(iy0, 0), Wj - 1);
                ty1 = imin(imax(iy1, 0), Wj - 1);
                ty2 = imin(imax(iy2, 0), Wj - 1);
            }

            int r0 = off + ty0 * Pj, r1 = off + ty1 * Pj, r2 = off + ty2 * Pj;
            float p00 = s_lo[r0 + tx0], p01 = s_lo[r0 + tx1], p02 = s_lo[r0 + tx2];
            float p10 = s_lo[r1 + tx0], p11 = s_lo[r1 + tx1], p12 = s_lo[r1 + tx2];
            float p20 = s_lo[r2 + tx0], p21 = s_lo[r2 + tx1], p22 = s_lo[r2 + tx2];
            float ra0 = ax0 * p00 + ax1 * p01 + ax2 * p02;
            float ra1 = ax0 * p10 + ax1 * p11 + ax2 * p12;
            float ra2 = ax0 * p20 + ax1 * p21 + ax2 * p22;
            float rb0 = bx0 * p00 + bx1 * p01 + bx2 * p02;
            float rb1 = bx0 * p10 + bx1 * p11 + bx2 * p12;
            float rb2 = bx0 * p20 + bx1 * p21 + bx2 * p22;
            float s_a = ay0 * ra0 + ay1 * ra1 + ay2 * ra2;
            float s_b = by0 * rb0 + by1 * rb1 + by2 * rb2;
            acc += fk[j] * s_b - 4.f * fk[j - 1] * s_a;

            x0p = x0j; y0p = y0j;
            ux0p = ux0j; ux1p = ux1j; uy0p = uy0j; uy1p = uy1j;
        }

        atomicAdd(&yrow[out], acc);
    }
}

extern "C" void kernel_launch(void* const* d_in, const int* in_sizes, int n_in,
                              void* d_out, int out_size, void* d_ws, size_t ws_size,
                              hipStream_t stream) {
    (void)in_sizes; (void)n_in; (void)d_ws; (void)ws_size;
    const float* x    = (const float*)d_in[0];
    const float* grid = (const float*)d_in[1];
    const float* feat = (const float*)d_in[2];
    const float* bias = (const float*)d_in[3];
    float* y = (float*)d_out;

    init_out_kernel<<<out_size / 256, 256, 0, stream>>>(bias, y);
    pyr_sample_kernel<<<2048, 256, 0, stream>>>(x, grid, feat, y);
}

// Round 4
// 455.663 us; speedup vs baseline: 1.4497x; 1.4497x over previous
//
#include <hip/hip_runtime.h>

// ---------------------------------------------------------------------------
// SpatialTransformerPyramid2d fused, round 4.
// N=64, c=32, H=W=128, outdims=4096, SCALE_N=4.
//
// Identity: sample(hi_{j-1}) = bilin(img_{j-1}) - 4*stencil_{j-1}(lo_j), and
// level-j bilinear taps lie inside the 3-tap stencil frame (proven:
// x0j - qx in {0,1}).  Per (out,ch): 4 global taps + 4 levels * 3x4 LDS taps.
//
// Round-4: per-out sampling weights are IDENTICAL across all (n,c) ->
// precompute once (weights_kernel) into d_ws (88 dwords/out = 1.44 MB),
// removing the ~120-inst serial weight chain from the hot loop.
//
// VGPR allocator rule (measured r1-r3): cap = floor(256 / waves_per_EU).
// (256,6) forced 40 VGPRs -> 1.6 GB spill traffic.  This kernel needs ~84
// -> MUST use __launch_bounds__(256,3).  LDS 45440 B -> 3 blocks/CU.
//
// LDS strides even (66/34/18/10) so each patch row = two aligned float2
// reads (ds_read2_b64); x-taps frame-shifted to an even 4-wide window.
// ---------------------------------------------------------------------------

#define P1 66
#define P2 34
#define P3 18
#define P4 10
#define OFF_LO1 0                      // 64*66 = 4224
#define OFF_LO2 4224                   // 32*34 = 1088
#define OFF_LO3 5312                   // 16*18 = 288
#define OFF_LO4 5600                   // 8*10  = 80
#define SLOT    5680                   // floats per channel (22720 B)

#define G_A 0.0613609f
#define G_B 0.2447700f
#define G_C 0.3877386f

#define WREC 22                        // float4s per out record (88 dwords)

static __device__ __forceinline__ float clampf(float v, float lo, float hi) {
    return fminf(fmaxf(v, lo), hi);
}
static __device__ __forceinline__ int imin(int a, int b) { return a < b ? a : b; }
static __device__ __forceinline__ int imax(int a, int b) { return a > b ? a : b; }

__global__ void init_out_kernel(const float* __restrict__ bias, float* __restrict__ y) {
    int i = blockIdx.x * blockDim.x + threadIdx.x;
    y[i] = bias[i & 4095];
}

// ---------------------------------------------------------------------------
// Per-out weight records (shared by all 2048 (n,c) images).
// dwords 0-3 : level-0 bilinear weights w00,w01,w10,w11
// dwords 4-7 : level-0 tap offsets (int as float bits)
// per level j=1..4 at 8+(j-1)*20:
//   [0:4]  AX[4]  a-weights in 4-wide frame      [4:8]  BX[4]  b-weights
//   [8:11] AY[3]+pad                              [12:15] BY[3]+pad
//   [16:19] R[3] row base dword offsets (int bits)+pad
// ---------------------------------------------------------------------------
__global__ void weights_kernel(const float* __restrict__ grid, float* __restrict__ ws) {
    int out = blockIdx.x * blockDim.x + threadIdx.x;
    if (out >= 4096) return;
    float xs = clampf(grid[2 * out + 0], -1.f, 1.f);
    float ys = clampf(grid[2 * out + 1], -1.f, 1.f);
    float* R = ws + (size_t)out * 88;

    // level 0
    float fx = (xs + 1.f) * 64.f - 0.5f;
    float fy = (ys + 1.f) * 64.f - 0.5f;
    float x0f = floorf(fx), y0f = floorf(fy);
    int x0 = (int)x0f, y0 = (int)y0f;
    float wx = fx - x0f, wy = fy - y0f;
    float ux0 = (x0 >= 0)      ? (1.f - wx) : 0.f;
    float ux1 = (x0 + 1 < 128) ? wx         : 0.f;
    float uy0 = (y0 >= 0)      ? (1.f - wy) : 0.f;
    float uy1 = (y0 + 1 < 128) ? wy         : 0.f;
    int cx0 = imax(x0, 0), cx1 = imin(x0 + 1, 127);
    int cy0 = imax(y0, 0), cy1 = imin(y0 + 1, 127);
    R[0] = ux0 * uy0; R[1] = ux1 * uy0; R[2] = ux0 * uy1; R[3] = ux1 * uy1;
    R[4] = __int_as_float(cy0 * 128 + cx0);
    R[5] = __int_as_float(cy0 * 128 + cx1);
    R[6] = __int_as_float(cy1 * 128 + cx0);
    R[7] = __int_as_float(cy1 * 128 + cx1);

    int   x0p = x0, y0p = y0;
    float ux0p = ux0, ux1p = ux1, uy0p = uy0, uy1p = uy1;

    const int offs[4]    = {OFF_LO1, OFF_LO2, OFF_LO3, OFF_LO4};
    const int strides[4] = {P1, P2, P3, P4};

    for (int j = 1; j <= 4; ++j) {
        const int Wj = 128 >> j, Pj = strides[j - 1], off = offs[j - 1];

        // a-weights (3-tap transposed-conv stencil from level j-1 corners)
        int qx; float a0, a1, a2;
        if (x0p & 1) { qx = (x0p - 1) >> 1;
            a0 = G_B * ux0p + G_A * ux1p; a1 = G_B * ux0p + G_C * ux1p; a2 = G_A * ux1p; }
        else         { qx = (x0p >> 1) - 1;
            a0 = G_A * ux0p; a1 = G_C * ux0p + G_B * ux1p; a2 = G_A * ux0p + G_B * ux1p; }
        int qy; float e0, e1, e2;
        if (y0p & 1) { qy = (y0p - 1) >> 1;
            e0 = G_B * uy0p + G_A * uy1p; e1 = G_B * uy0p + G_C * uy1p; e2 = G_A * uy1p; }
        else         { qy = (y0p >> 1) - 1;
            e0 = G_A * uy0p; e1 = G_C * uy0p + G_B * uy1p; e2 = G_A * uy0p + G_B * uy1p; }

        // level-j bilinear
        float half = (float)(Wj >> 1);
        float fxj = (xs + 1.f) * half - 0.5f;
        float fyj = (ys + 1.f) * half - 0.5f;
        float x0jf = floorf(fxj), y0jf = floorf(fyj);
        int x0j = (int)x0jf, y0j = (int)y0jf;
        float wxj = fxj - x0jf, wyj = fyj - y0jf;
        float ux0j = (x0j >= 0)     ? (1.f - wxj) : 0.f;
        float ux1j = (x0j + 1 < Wj) ? wxj         : 0.f;
        float uy0j = (y0j >= 0)     ? (1.f - wyj) : 0.f;
        float uy1j = (y0j + 1 < Wj) ? wyj         : 0.f;

        // even 4-wide x frame covering all in-bounds taps
        int bxb = qx & ~1;
        bxb = imin(imax(bxb, 0), Wj - 4);

        float* L = R + 8 + (j - 1) * 20;
#pragma unroll
        for (int t = 0; t < 4; ++t) {
            int col = bxb + t;
            int s = col - qx;
            float av = (s == 0) ? a0 : (s == 1) ? a1 : (s == 2) ? a2 : 0.f;
            if (s < 0 || s > 2) av = 0.f;
            int sb = col - x0j;
            float bv = (sb == 0) ? ux0j : (sb == 1) ? ux1j : 0.f;
            L[t] = av;
            L[4 + t] = bv;
        }
#pragma unroll
        for (int t = 0; t < 3; ++t) {
            int row = qy + t;
            bool v = (row >= 0) && (row < Wj);
            float av = (t == 0) ? e0 : (t == 1) ? e1 : e2;
            L[8 + t] = v ? av : 0.f;
            int sb = row - y0j;
            L[12 + t] = (sb == 0) ? uy0j : (sb == 1) ? uy1j : 0.f;
            int rc = imin(imax(row, 0), Wj - 1);
            L[16 + t] = __int_as_float(off + rc * Pj + bxb);
        }
        L[11] = 0.f; L[15] = 0.f; L[19] = 0.f;

        x0p = x0j; y0p = y0j;
        ux0p = ux0j; ux1p = ux1j; uy0p = uy0j; uy1p = uy1j;
    }
}

// smooth+downsample one point from LDS src (stride, logical S x S, zero pad)
static __device__ __forceinline__ float down_pt_lds(const float* s, int stride, int S,
                                                    int i, int j) {
    const float g1[5] = {G_A, G_B, G_C, G_B, G_A};
    int by = 2 * i - 2, bx = 2 * j - 2;
    float acc = 0.f;
    if (by >= 0 && by + 4 < S && bx >= 0 && bx + 4 < S) {
#pragma unroll
        for (int dy = 0; dy < 5; ++dy) {
            const float* r = s + (by + dy) * stride + bx;
            acc += g1[dy] * (G_A * (r[0] + r[4]) + G_B * (r[1] + r[3]) + G_C * r[2]);
        }
    } else {
#pragma unroll
        for (int dy = 0; dy < 5; ++dy) {
            int yy = by + dy;
            if ((unsigned)yy < (unsigned)S) {
#pragma unroll
                for (int dx = 0; dx < 5; ++dx) {
                    int xx = bx + dx;
                    if ((unsigned)xx < (unsigned)S)
                        acc += g1[dy] * g1[dx] * s[yy * stride + xx];
                }
            }
        }
    }
    return acc;
}

__global__ __launch_bounds__(256, 3) void pyr_sample_kernel(
    const float* __restrict__ x, const float* __restrict__ wrec,
    const float* __restrict__ feat, float* __restrict__ y)
{
    __shared__ float s_lo[2 * SLOT];
    const int tid = threadIdx.x;
    const int n   = blockIdx.x >> 4;        // 64
    const int c0  = (blockIdx.x & 15) << 1; // 16 pairs
    const float* imgA = x + ((size_t)(n * 32 + c0) << 14);
    const float* imgB = imgA + 16384;

    const float g1[5] = {G_A, G_B, G_C, G_B, G_A};

    // ---- phase 1: lo1 (64x64) x 2ch, runs of 4 adjacent points ------------
    for (int r = tid; r < 2048; r += 256) {
        int gi = r >> 10, p = r & 1023;
        int i = p >> 4, j0 = (p & 15) << 2;
        const float* img = gi ? imgB : imgA;
        int by = 2 * i - 2, bx = 2 * j0 - 2;
        float acc[4] = {0.f, 0.f, 0.f, 0.f};
        if (i >= 1 && i <= 62 && j0 >= 4 && j0 <= 56) {
#pragma unroll
            for (int dy = 0; dy < 5; ++dy) {
                const float* row = img + (by + dy) * 128 + bx;
                float v[11];
#pragma unroll
                for (int t = 0; t < 11; ++t) v[t] = row[t];
                float g = g1[dy];
#pragma unroll
                for (int jj = 0; jj < 4; ++jj) {
                    float h = G_A * (v[2 * jj] + v[2 * jj + 4]) +
                              G_B * (v[2 * jj + 1] + v[2 * jj + 3]) +
                              G_C * v[2 * jj + 2];
                    acc[jj] += g * h;
                }
            }
        } else {
#pragma unroll
            for (int dy = 0; dy < 5; ++dy) {
                int yy = by + dy;
                if ((unsigned)yy < 128u) {
#pragma unroll
                    for (int t = 0; t < 11; ++t) {
                        int xx = bx + t;
                        if ((unsigned)xx < 128u) {
                            float v = img[yy * 128 + xx];
#pragma unroll
                            for (int jj = 0; jj < 4; ++jj) {
                                int dx = t - 2 * jj;
                                if (dx >= 0 && dx <= 4) acc[jj] += g1[dy] * g1[dx] * v;
                            }
                        }
                    }
                }
            }
        }
        int base = gi * SLOT + OFF_LO1 + i * P1 + j0;   // even (P1 even, j0%4==0)
        *(float2*)&s_lo[base]     = make_float2(acc[0], acc[1]);
        *(float2*)&s_lo[base + 2] = make_float2(acc[2], acc[3]);
    }
    __syncthreads();

    // ---- phase 2: lo2 (32x32) x 2ch ----
    for (int pos = tid; pos < 2048; pos += 256) {
        int gi = pos >> 10, p = pos & 1023;
        int i = p >> 5, j = p & 31;
        int b = gi * SLOT;
        s_lo[b + OFF_LO2 + i * P2 + j] = down_pt_lds(s_lo + b + OFF_LO1, P1, 64, i, j);
    }
    __syncthreads();

    // ---- phase 3: lo3 (16x16) x 2ch ----
    for (int pos = tid; pos < 512; pos += 256) {
        int gi = pos >> 8, p = pos & 255;
        int i = p >> 4, j = p & 15;
        int b = gi * SLOT;
        s_lo[b + OFF_LO3 + i * P3 + j] = down_pt_lds(s_lo + b + OFF_LO2, P2, 32, i, j);
    }
    __syncthreads();

    // ---- phase 4: lo4 (8x8) x 2ch ----
    if (tid < 128) {
        int gi = tid >> 6, p = tid & 63;
        int i = p >> 3, j = p & 7;
        int b = gi * SLOT;
        s_lo[b + OFF_LO4 + i * P4 + j] = down_pt_lds(s_lo + b + OFF_LO3, P3, 16, i, j);
    }
    __syncthreads();

    // ---- phase 5: sample + contract using precomputed weights -------------
    float* yrow = y + ((size_t)n << 12);
    for (int out = tid; out < 4096; out += 256) {
        const float4* R = (const float4*)(wrec + (size_t)out * 88);
        float4 w0 = R[0];
        float4 t1 = R[1];
        int o00 = __float_as_int(t1.x), o01 = __float_as_int(t1.y);
        int o10 = __float_as_int(t1.z), o11 = __float_as_int(t1.w);

        float fA_prev = feat[((size_t)c0 << 12) + out];
        float fB_prev = feat[((size_t)(c0 + 1) << 12) + out];

        float vA = w0.x * imgA[o00] + w0.y * imgA[o01] + w0.z * imgA[o10] + w0.w * imgA[o11];
        float vB = w0.x * imgB[o00] + w0.y * imgB[o01] + w0.z * imgB[o10] + w0.w * imgB[o11];
        float accA = fA_prev * vA;
        float accB = fB_prev * vB;

#pragma unroll
        for (int j = 1; j <= 4; ++j) {
            const float4 axw = R[2 + 5 * (j - 1) + 0];
            const float4 bxw = R[2 + 5 * (j - 1) + 1];
            const float4 ayw = R[2 + 5 * (j - 1) + 2];
            const float4 byw = R[2 + 5 * (j - 1) + 3];
            const float4 rrf = R[2 + 5 * (j - 1) + 4];
            int r0 = __float_as_int(rrf.x);
            int r1 = __float_as_int(rrf.y);
            int r2 = __float_as_int(rrf.z);

            float fA_cur = feat[((size_t)(j * 32 + c0) << 12) + out];
            float fB_cur = feat[((size_t)(j * 32 + c0 + 1) << 12) + out];

#pragma unroll
            for (int gi = 0; gi < 2; ++gi) {
                const int b = gi * SLOT;
                float2 p0a = *(const float2*)&s_lo[b + r0];
                float2 p0b = *(const float2*)&s_lo[b + r0 + 2];
                float2 p1a = *(const float2*)&s_lo[b + r1];
                float2 p1b = *(const float2*)&s_lo[b + r1 + 2];
                float2 p2a = *(const float2*)&s_lo[b + r2];
                float2 p2b = *(const float2*)&s_lo[b + r2 + 2];
                float ra0 = axw.x * p0a.x + axw.y * p0a.y + axw.z * p0b.x + axw.w * p0b.y;
                float ra1 = axw.x * p1a.x + axw.y * p1a.y + axw.z * p1b.x + axw.w * p1b.y;
                float ra2 = axw.x * p2a.x + axw.y * p2a.y + axw.z * p2b.x + axw.w * p2b.y;
                float rb0 = bxw.x * p0a.x + bxw.y * p0a.y + bxw.z * p0b.x + bxw.w * p0b.y;
                float rb1 = bxw.x * p1a.x + bxw.y * p1a.y + bxw.z * p1b.x + bxw.w * p1b.y;
                float rb2 = bxw.x * p2a.x + bxw.y * p2a.y + bxw.z * p2b.x + bxw.w * p2b.y;
                float sa = ayw.x * ra0 + ayw.y * ra1 + ayw.z * ra2;
                float sb = byw.x * rb0 + byw.y * rb1 + byw.z * rb2;
                if (gi == 0) accA += fA_cur * sb - 4.f * fA_prev * sa;
                else         accB += fB_cur * sb - 4.f * fB_prev * sa;
            }
            fA_prev = fA_cur; fB_prev = fB_cur;
        }
        atomicAdd(&yrow[out], accA + accB);
    }
}

extern "C" void kernel_launch(void* const* d_in, const int* in_sizes, int n_in,
                              void* d_out, int out_size, void* d_ws, size_t ws_size,
                              hipStream_t stream) {
    (void)in_sizes; (void)n_in; (void)ws_size;
    const float* x    = (const float*)d_in[0];
    const float* grid = (const float*)d_in[1];
    const float* feat = (const float*)d_in[2];
    const float* bias = (const float*)d_in[3];
    float* y  = (float*)d_out;
    float* ws = (float*)d_ws;

    weights_kernel<<<16, 256, 0, stream>>>(grid, ws);
    init_out_kernel<<<out_size / 256, 256, 0, stream>>>(bias, y);
    pyr_sample_kernel<<<1024, 256, 0, stream>>>(x, ws, feat, y);
}

// Round 5
// 403.671 us; speedup vs baseline: 1.6364x; 1.1288x over previous
//
#include <hip/hip_runtime.h>

// ---------------------------------------------------------------------------
// SpatialTransformerPyramid2d fused, round 5.
// N=64, c=32, H=W=128, outdims=4096, SCALE_N=4.
//
// Identity: sample(hi_{j-1}) = bilin(img_{j-1}) - 4*stencil_{j-1}(lo_j);
// level-j bilinear taps lie inside the 3-tap stencil frame -> one 3x4 patch
// per level serves both terms.  Per (out,ch): 4 global taps + 4x12 LDS taps.
//
// Round-5 changes (latency attack; r4 was 27% occupancy, VALU 78% idle):
//  1. 1 channel/block (2048 blocks, LDS 22720 B).  At 84 VGPRs the HW wave
//     ceiling is 4 waves/SIMD (16/CU); 2-ch LDS (45.5 KB) capped us at 12.
//     Now LDS allows 7 blocks, VGPR allows 4 -> 16 waves/CU.
//  2. Weight table transposed to SoA: component m of record for `out` lives
//     at float4 index m*4096+out.  Lane stride 16 B -> every wave-load is
//     1 KB contiguous (was AoS stride 352 B = 64 lines per load).
//
// VGPR allocator rule (measured r1-r4): __launch_bounds__(256,3) -> 84 regs,
// no spill.  (256,6) forces 40 regs -> GB-scale scratch spills.  Keep (256,3).
// ---------------------------------------------------------------------------

#define P1 66
#define P2 34
#define P3 18
#define P4 10
#define OFF_LO1 0                      // 64*66 = 4224
#define OFF_LO2 4224                   // 32*34 = 1088
#define OFF_LO3 5312                   // 16*18 = 288
#define OFF_LO4 5600                   // 8*10  = 80
#define SLOT    5680                   // floats per channel (22720 B)

#define G_A 0.0613609f
#define G_B 0.2447700f
#define G_C 0.3877386f

static __device__ __forceinline__ float clampf(float v, float lo, float hi) {
    return fminf(fmaxf(v, lo), hi);
}
static __device__ __forceinline__ int imin(int a, int b) { return a < b ? a : b; }
static __device__ __forceinline__ int imax(int a, int b) { return a > b ? a : b; }

__global__ void init_out_kernel(const float* __restrict__ bias, float* __restrict__ y) {
    int i = blockIdx.x * blockDim.x + threadIdx.x;
    y[i] = bias[i & 4095];
}

// ---------------------------------------------------------------------------
// SoA weight table: float4 component m for point `out` at ws4[m*4096 + out].
//  m=0 : level-0 bilinear weights w00,w01,w10,w11
//  m=1 : level-0 tap offsets (int bits)
//  m=2+5(j-1)+{0,1,2,3,4} : AX[4], BX[4], AY[3]+pad, BY[3]+pad, rowoffs[3]+pad
// ---------------------------------------------------------------------------
__global__ void weights_kernel(const float* __restrict__ grid, float* __restrict__ ws) {
    int out = blockIdx.x * blockDim.x + threadIdx.x;
    if (out >= 4096) return;
    float xs = clampf(grid[2 * out + 0], -1.f, 1.f);
    float ys = clampf(grid[2 * out + 1], -1.f, 1.f);
    float rec[88];

    // level 0
    float fx = (xs + 1.f) * 64.f - 0.5f;
    float fy = (ys + 1.f) * 64.f - 0.5f;
    float x0f = floorf(fx), y0f = floorf(fy);
    int x0 = (int)x0f, y0 = (int)y0f;
    float wx = fx - x0f, wy = fy - y0f;
    float ux0 = (x0 >= 0)      ? (1.f - wx) : 0.f;
    float ux1 = (x0 + 1 < 128) ? wx         : 0.f;
    float uy0 = (y0 >= 0)      ? (1.f - wy) : 0.f;
    float uy1 = (y0 + 1 < 128) ? wy         : 0.f;
    int cx0 = imax(x0, 0), cx1 = imin(x0 + 1, 127);
    int cy0 = imax(y0, 0), cy1 = imin(y0 + 1, 127);
    rec[0] = ux0 * uy0; rec[1] = ux1 * uy0; rec[2] = ux0 * uy1; rec[3] = ux1 * uy1;
    rec[4] = __int_as_float(cy0 * 128 + cx0);
    rec[5] = __int_as_float(cy0 * 128 + cx1);
    rec[6] = __int_as_float(cy1 * 128 + cx0);
    rec[7] = __int_as_float(cy1 * 128 + cx1);

    int   x0p = x0, y0p = y0;
    float ux0p = ux0, ux1p = ux1, uy0p = uy0, uy1p = uy1;

    const int offs[4]    = {OFF_LO1, OFF_LO2, OFF_LO3, OFF_LO4};
    const int strides[4] = {P1, P2, P3, P4};

    for (int j = 1; j <= 4; ++j) {
        const int Wj = 128 >> j, Pj = strides[j - 1], off = offs[j - 1];

        // a-weights (3-tap transposed-conv stencil from level j-1 corners)
        int qx; float a0, a1, a2;
        if (x0p & 1) { qx = (x0p - 1) >> 1;
            a0 = G_B * ux0p + G_A * ux1p; a1 = G_B * ux0p + G_C * ux1p; a2 = G_A * ux1p; }
        else         { qx = (x0p >> 1) - 1;
            a0 = G_A * ux0p; a1 = G_C * ux0p + G_B * ux1p; a2 = G_A * ux0p + G_B * ux1p; }
        int qy; float e0, e1, e2;
        if (y0p & 1) { qy = (y0p - 1) >> 1;
            e0 = G_B * uy0p + G_A * uy1p; e1 = G_B * uy0p + G_C * uy1p; e2 = G_A * uy1p; }
        else         { qy = (y0p >> 1) - 1;
            e0 = G_A * uy0p; e1 = G_C * uy0p + G_B * uy1p; e2 = G_A * uy0p + G_B * uy1p; }

        // level-j bilinear
        float half = (float)(Wj >> 1);
        float fxj = (xs + 1.f) * half - 0.5f;
        float fyj = (ys + 1.f) * half - 0.5f;
        float x0jf = floorf(fxj), y0jf = floorf(fyj);
        int x0j = (int)x0jf, y0j = (int)y0jf;
        float wxj = fxj - x0jf, wyj = fyj - y0jf;
        float ux0j = (x0j >= 0)     ? (1.f - wxj) : 0.f;
        float ux1j = (x0j + 1 < Wj) ? wxj         : 0.f;
        float uy0j = (y0j >= 0)     ? (1.f - wyj) : 0.f;
        float uy1j = (y0j + 1 < Wj) ? wyj         : 0.f;

        // even 4-wide x frame covering all in-bounds taps
        int bxb = qx & ~1;
        bxb = imin(imax(bxb, 0), Wj - 4);

        float* L = rec + 8 + (j - 1) * 20;
#pragma unroll
        for (int t = 0; t < 4; ++t) {
            int col = bxb + t;
            int s = col - qx;
            float av = (s == 0) ? a0 : (s == 1) ? a1 : (s == 2) ? a2 : 0.f;
            if (s < 0 || s > 2) av = 0.f;
            int sb = col - x0j;
            float bv = (sb == 0) ? ux0j : (sb == 1) ? ux1j : 0.f;
            L[t] = av;
            L[4 + t] = bv;
        }
#pragma unroll
        for (int t = 0; t < 3; ++t) {
            int row = qy + t;
            bool v = (row >= 0) && (row < Wj);
            float av = (t == 0) ? e0 : (t == 1) ? e1 : e2;
            L[8 + t] = v ? av : 0.f;
            int sb = row - y0j;
            L[12 + t] = (sb == 0) ? uy0j : (sb == 1) ? uy1j : 0.f;
            int rc = imin(imax(row, 0), Wj - 1);
            L[16 + t] = __int_as_float(off + rc * Pj + bxb);
        }
        L[11] = 0.f; L[15] = 0.f; L[19] = 0.f;

        x0p = x0j; y0p = y0j;
        ux0p = ux0j; ux1p = ux1j; uy0p = uy0j; uy1p = uy1j;
    }

    // scatter to SoA
    float4* W = (float4*)ws;
#pragma unroll
    for (int m = 0; m < 22; ++m) {
        W[m * 4096 + out] = make_float4(rec[4 * m], rec[4 * m + 1],
                                        rec[4 * m + 2], rec[4 * m + 3]);
    }
}

// smooth+downsample one point from LDS src (stride, logical S x S, zero pad)
static __device__ __forceinline__ float down_pt_lds(const float* s, int stride, int S,
                                                    int i, int j) {
    const float g1[5] = {G_A, G_B, G_C, G_B, G_A};
    int by = 2 * i - 2, bx = 2 * j - 2;
    float acc = 0.f;
    if (by >= 0 && by + 4 < S && bx >= 0 && bx + 4 < S) {
#pragma unroll
        for (int dy = 0; dy < 5; ++dy) {
            const float* r = s + (by + dy) * stride + bx;
            acc += g1[dy] * (G_A * (r[0] + r[4]) + G_B * (r[1] + r[3]) + G_C * r[2]);
        }
    } else {
#pragma unroll
        for (int dy = 0; dy < 5; ++dy) {
            int yy = by + dy;
            if ((unsigned)yy < (unsigned)S) {
#pragma unroll
                for (int dx = 0; dx < 5; ++dx) {
                    int xx = bx + dx;
                    if ((unsigned)xx < (unsigned)S)
                        acc += g1[dy] * g1[dx] * s[yy * stride + xx];
                }
            }
        }
    }
    return acc;
}

__global__ __launch_bounds__(256, 3) void pyr_sample_kernel(
    const float* __restrict__ x, const float* __restrict__ wrec,
    const float* __restrict__ feat, float* __restrict__ y)
{
    __shared__ float s_lo[SLOT];
    const int tid = threadIdx.x;
    const int n   = blockIdx.x >> 5;   // 64
    const int c   = blockIdx.x & 31;   // 32
    const float* img = x + ((size_t)(n * 32 + c) << 14);

    const float g1[5] = {G_A, G_B, G_C, G_B, G_A};

    // ---- phase 1: lo1 (64x64), runs of 4 adjacent points ------------------
    for (int r = tid; r < 1024; r += 256) {
        int i = r >> 4, j0 = (r & 15) << 2;
        int by = 2 * i - 2, bx = 2 * j0 - 2;
        float acc[4] = {0.f, 0.f, 0.f, 0.f};
        if (i >= 1 && i <= 62 && j0 >= 4 && j0 <= 56) {
#pragma unroll
            for (int dy = 0; dy < 5; ++dy) {
                const float* row = img + (by + dy) * 128 + bx;
                float v[11];
#pragma unroll
                for (int t = 0; t < 11; ++t) v[t] = row[t];
                float g = g1[dy];
#pragma unroll
                for (int jj = 0; jj < 4; ++jj) {
                    float h = G_A * (v[2 * jj] + v[2 * jj + 4]) +
                              G_B * (v[2 * jj + 1] + v[2 * jj + 3]) +
                              G_C * v[2 * jj + 2];
                    acc[jj] += g * h;
                }
            }
        } else {
#pragma unroll
            for (int dy = 0; dy < 5; ++dy) {
                int yy = by + dy;
                if ((unsigned)yy < 128u) {
#pragma unroll
                    for (int t = 0; t < 11; ++t) {
                        int xx = bx + t;
                        if ((unsigned)xx < 128u) {
                            float v = img[yy * 128 + xx];
#pragma unroll
                            for (int jj = 0; jj < 4; ++jj) {
                                int dx = t - 2 * jj;
                                if (dx >= 0 && dx <= 4) acc[jj] += g1[dy] * g1[dx] * v;
                            }
                        }
                    }
                }
            }
        }
        int base = OFF_LO1 + i * P1 + j0;   // even (P1 even, j0%4==0)
        *(float2*)&s_lo[base]     = make_float2(acc[0], acc[1]);
        *(float2*)&s_lo[base + 2] = make_float2(acc[2], acc[3]);
    }
    __syncthreads();

    // ---- phase 2: lo2 (32x32) ----
    for (int p = tid; p < 1024; p += 256) {
        int i = p >> 5, j = p & 31;
        s_lo[OFF_LO2 + i * P2 + j] = down_pt_lds(s_lo + OFF_LO1, P1, 64, i, j);
    }
    __syncthreads();

    // ---- phase 3: lo3 (16x16) ----
    {
        int i = tid >> 4, j = tid & 15;
        s_lo[OFF_LO3 + i * P3 + j] = down_pt_lds(s_lo + OFF_LO2, P2, 32, i, j);
    }
    __syncthreads();

    // ---- phase 4: lo4 (8x8) ----
    if (tid < 64) {
        int i = tid >> 3, j = tid & 7;
        s_lo[OFF_LO4 + i * P4 + j] = down_pt_lds(s_lo + OFF_LO3, P3, 16, i, j);
    }
    __syncthreads();

    // ---- phase 5: sample + contract using SoA precomputed weights ---------
    const float4* W = (const float4*)wrec;
    float* yrow = y + ((size_t)n << 12);
    for (int out = tid; out < 4096; out += 256) {
        float4 w0 = W[out];                 // m=0
        float4 t1 = W[4096 + out];          // m=1
        int o00 = __float_as_int(t1.x), o01 = __float_as_int(t1.y);
        int o10 = __float_as_int(t1.z), o11 = __float_as_int(t1.w);

        float f_prev = feat[((size_t)c << 12) + out];
        float v0 = w0.x * img[o00] + w0.y * img[o01] + w0.z * img[o10] + w0.w * img[o11];
        float acc = f_prev * v0;

#pragma unroll
        for (int j = 1; j <= 4; ++j) {
            const int mb = (2 + 5 * (j - 1)) * 4096 + out;
            const float4 axw = W[mb];
            const float4 bxw = W[mb + 4096];
            const float4 ayw = W[mb + 2 * 4096];
            const float4 byw = W[mb + 3 * 4096];
            const float4 rrf = W[mb + 4 * 4096];
            int r0 = __float_as_int(rrf.x);
            int r1 = __float_as_int(rrf.y);
            int r2 = __float_as_int(rrf.z);

            float f_cur = feat[((size_t)(j * 32 + c) << 12) + out];

            float2 p0a = *(const float2*)&s_lo[r0];
            float2 p0b = *(const float2*)&s_lo[r0 + 2];
            float2 p1a = *(const float2*)&s_lo[r1];
            float2 p1b = *(const float2*)&s_lo[r1 + 2];
            float2 p2a = *(const float2*)&s_lo[r2];
            float2 p2b = *(const float2*)&s_lo[r2 + 2];
            float ra0 = axw.x * p0a.x + axw.y * p0a.y + axw.z * p0b.x + axw.w * p0b.y;
            float ra1 = axw.x * p1a.x + axw.y * p1a.y + axw.z * p1b.x + axw.w * p1b.y;
            float ra2 = axw.x * p2a.x + axw.y * p2a.y + axw.z * p2b.x + axw.w * p2b.y;
            float rb0 = bxw.x * p0a.x + bxw.y * p0a.y + bxw.z * p0b.x + bxw.w * p0b.y;
            float rb1 = bxw.x * p1a.x + bxw.y * p1a.y + bxw.z * p1b.x + bxw.w * p1b.y;
            float rb2 = bxw.x * p2a.x + bxw.y * p2a.y + bxw.z * p2b.x + bxw.w * p2b.y;
            float sa = ayw.x * ra0 + ayw.y * ra1 + ayw.z * ra2;
            float sb = byw.x * rb0 + byw.y * rb1 + byw.z * rb2;
            acc += f_cur * sb - 4.f * f_prev * sa;
            f_prev = f_cur;
        }
        atomicAdd(&yrow[out], acc);
    }
}

extern "C" void kernel_launch(void* const* d_in, const int* in_sizes, int n_in,
                              void* d_out, int out_size, void* d_ws, size_t ws_size,
                              hipStream_t stream) {
    (void)in_sizes; (void)n_in; (void)ws_size;
    const float* x    = (const float*)d_in[0];
    const float* grid = (const float*)d_in[1];
    const float* feat = (const float*)d_in[2];
    const float* bias = (const float*)d_in[3];
    float* y  = (float*)d_out;
    float* ws = (float*)d_ws;

    weights_kernel<<<16, 256, 0, stream>>>(grid, ws);
    init_out_kernel<<<out_size / 256, 256, 0, stream>>>(bias, y);
    pyr_sample_kernel<<<2048, 256, 0, stream>>>(x, ws, feat, y);
}